// Round 5
// baseline (579.396 us; speedup 1.0000x reference)
//
#include <hip/hip_runtime.h>

#define N_NODES 100000
#define N_EDGES 3200000
#define ROWS_PAD 100032   // multiple of 64 for GEMM tiling
#define N_BUCKETS 782     // ceil(100000/128)
#define BUCKET_SHIFT 7

typedef __attribute__((ext_vector_type(8))) short bf16x8;
typedef __attribute__((ext_vector_type(4))) float f32x4;
typedef __attribute__((ext_vector_type(2))) float f32x2;

__device__ __forceinline__ unsigned short f2bf(float f) {
    unsigned u = __float_as_uint(f);
    unsigned r = (u + 0x7fffu + ((u >> 16) & 1u)) >> 16;  // round-to-nearest-even
    return (unsigned short)r;
}
__device__ __forceinline__ float bflo(unsigned u) { return __uint_as_float(u << 16); }
__device__ __forceinline__ float bfhi(unsigned u) { return __uint_as_float(u & 0xffff0000u); }

// ---- convert x fp32 -> fp8 e4m3 [ROWS_PAD,128]; persistent grid-stride, 16B/thread/iter ----
__global__ void __launch_bounds__(256) k_convert_x(const float* __restrict__ x,
                                                   unsigned* __restrict__ xf8) {
    const int QTOT = ROWS_PAD * 32;            // 4-channel quads
    for (int q = blockIdx.x * 256 + threadIdx.x; q < QTOT; q += 1024 * 256) {
        int r = q >> 5;
        f32x4 f = {0.f, 0.f, 0.f, 0.f};
        if (r < N_NODES) f = *(const f32x4*)(x + 4 * (size_t)q);
        int pk = __builtin_amdgcn_cvt_pk_fp8_f32(f.x, f.y, 0, false);
        pk = __builtin_amdgcn_cvt_pk_fp8_f32(f.z, f.w, pk, true);
        xf8[q] = (unsigned)pk;
    }
}

// ---- convert+transpose W [4][k][c] fp32 -> WT [4][c][k] bf16 ----
__global__ void k_convert_w(const float* __restrict__ w, unsigned short* __restrict__ wt) {
    int i = blockIdx.x * 256 + threadIdx.x;          // 65536 total
    int m = i >> 14, rem = i & 16383, k = rem >> 7, c = rem & 127;
    wt[(m << 14) + (c << 7) + k] = f2bf(w[i]);
}

// ---- coarse bucket histogram (row>>7), LDS-aggregated ----
__global__ void __launch_bounds__(256) k_bhist(const int* __restrict__ ei, int* __restrict__ bcnt) {
    __shared__ int h[N_BUCKETS];
    for (int i = threadIdx.x; i < N_BUCKETS; i += 256) h[i] = 0;
    __syncthreads();
    int base = blockIdx.x * 8192;
#pragma unroll
    for (int i = 0; i < 32; ++i) {
        int e = base + threadIdx.x + i * 256;
        if (e < N_EDGES) atomicAdd(&h[ei[e] >> BUCKET_SHIFT], 1);
    }
    __syncthreads();
    for (int i = threadIdx.x; i < N_BUCKETS; i += 256)
        if (h[i]) atomicAdd(&bcnt[i], h[i]);
}

// ---- one-block exclusive scan of bucket counts; also zero ep's 64 pad slots past E ----
__global__ void __launch_bounds__(1024) k_bscan(const int* __restrict__ bcnt,
                                                int* __restrict__ bbase,
                                                int* __restrict__ bcursor,
                                                int* __restrict__ rowstart,
                                                int2* __restrict__ ep) {
    __shared__ int s[1024];
    int t = threadIdx.x;
    int v = (t < N_BUCKETS) ? bcnt[t] : 0;
    s[t] = v;
    __syncthreads();
    for (int off = 1; off < 1024; off <<= 1) {
        int tv = (t >= off) ? s[t - off] : 0;
        __syncthreads();
        s[t] += tv;
        __syncthreads();
    }
    if (t < N_BUCKETS) {
        int ex = s[t] - v;
        bbase[t] = ex;
        bcursor[t] = ex;
    }
    if (t == 0) {
        bbase[N_BUCKETS] = N_EDGES;
        rowstart[N_NODES] = N_EDGES;
    }
    // zero pad entries so the masked tail batch can over-read valid memory
    if (t < 64) ep[N_EDGES + t] = make_int2(0, 0);
}

// ---- pass 1: bin edges by coarse bucket; per-block run reservation -> L2-local scatter ----
__global__ void __launch_bounds__(1024) k_bin(const int* __restrict__ ei,
                                              const float* __restrict__ lap,
                                              int* __restrict__ bcursor,
                                              uint2* __restrict__ ep_tmp) {
    __shared__ int h[N_BUCKETS];
    __shared__ int runbase[N_BUCKETS];
    for (int i = threadIdx.x; i < N_BUCKETS; i += 1024) h[i] = 0;
    __syncthreads();
    int base = blockIdx.x * 16384;
#pragma unroll
    for (int i = 0; i < 16; ++i) {
        int e = base + threadIdx.x + i * 1024;
        if (e < N_EDGES) atomicAdd(&h[ei[e] >> BUCKET_SHIFT], 1);
    }
    __syncthreads();
    for (int i = threadIdx.x; i < N_BUCKETS; i += 1024) {
        int c = h[i];
        runbase[i] = c ? atomicAdd(&bcursor[i], c) : 0;
        h[i] = 0;   // reuse as local cursor
    }
    __syncthreads();
#pragma unroll
    for (int i = 0; i < 16; ++i) {
        int e = base + threadIdx.x + i * 1024;
        if (e < N_EDGES) {
            int row = ei[e], col = ei[N_EDGES + e];
            int b = row >> BUCKET_SHIFT;
            int p = runbase[b] + atomicAdd(&h[b], 1);
            ep_tmp[p] = make_uint2(((unsigned)(row & 127) << 17) | (unsigned)col,
                                   __float_as_uint(lap[e]));
        }
    }
}

// ---- pass 2: per-bucket row sort in LDS; emit rowstart + final ep ----
#define ST_CAP 5120
__global__ void __launch_bounds__(256) k_rsort(const uint2* __restrict__ ep_tmp,
                                               const int* __restrict__ bbase,
                                               int* __restrict__ rowstart,
                                               int2* __restrict__ ep) {
    __shared__ uint2 st[ST_CAP];
    __shared__ int h[128];
    __shared__ int lcur[128];
    int b = blockIdx.x;
    int base = bbase[b], end = bbase[b + 1];
    int n = end - base;
    if (n > ST_CAP) n = ST_CAP;   // statistically unreachable
    for (int i = threadIdx.x; i < n; i += 256) st[i] = ep_tmp[base + i];
    if (threadIdx.x < 128) h[threadIdx.x] = 0;
    __syncthreads();
    for (int i = threadIdx.x; i < n; i += 256) atomicAdd(&h[st[i].x >> 17], 1);
    __syncthreads();
    int t = threadIdx.x;
    int v = (t < 128) ? h[t] : 0;
    for (int off = 1; off < 128; off <<= 1) {
        int tv = (t < 128 && t >= off) ? h[t - off] : 0;
        __syncthreads();
        if (t < 128) h[t] += tv;
        __syncthreads();
    }
    if (t < 128) {
        int ex = h[t] - v;
        int r = (b << BUCKET_SHIFT) + t;
        if (r < N_NODES) rowstart[r] = base + ex;
        lcur[t] = base + ex;
    }
    __syncthreads();
    for (int i = threadIdx.x; i < n; i += 256) {
        uint2 s = st[i];
        int r = s.x >> 17;
        int p = atomicAdd(&lcur[r], 1);
        ep[p] = make_int2((int)(s.x & 0x1FFFFu), (int)s.y);
    }
}

// ---- SpMM gather (fp8 source), QUADRANT edition ----
// TA lane-address minimization: 16-lane dwordx2 gathers (4 edges/instr), one
// per-lane ep load per 16 edges + ds_bpermute distribution (LDS pipe).
// zmode: 0 = none, 1 = bf16 z, 3 = fp32 z.
__global__ void __launch_bounds__(256) k_spmm8(
    const unsigned char* __restrict__ xs, const void* __restrict__ z, int zmode,
    unsigned* __restrict__ y8, uint2* __restrict__ yb,
    const int* __restrict__ rowstart, const int2* __restrict__ ep, float a, float b)
{
    int wv = threadIdx.x >> 6, lane = threadIdx.x & 63;
    int r = blockIdx.x * 4 + wv;
    if (r >= N_NODES) return;    // pad rows never stored to out (masked in GEMM)
    int q = lane >> 4, s = lane & 15;
    unsigned vs8 = (unsigned)s * 8u;
    // bpermute byte-addrs: round u pulls from source lane u*4+q
    int bp0 = (q) * 4, bp1 = (4 + q) * 4, bp2 = (8 + q) * 4, bp3 = (12 + q) * 4;
    float acc0 = 0.f, acc1 = 0.f, acc2 = 0.f, acc3 = 0.f;
    float acc4 = 0.f, acc5 = 0.f, acc6 = 0.f, acc7 = 0.f;
    int e0 = rowstart[r], e1 = rowstart[r + 1];
    int cnt = e1 - e0;
    if (cnt > 0) {
        int niter = (cnt + 15) >> 4;      // 16 edges per stage
        int nfull = cnt >> 4;             // stages with no out-of-range slot
        const char* epb = (const char*)ep;

#define LOADEP(p, itv) do {                                              \
        int _idx = e0 + (itv) * 16 + s;                                  \
        int2 _t = *(const int2*)(epb + (unsigned)_idx * 8u);             \
        if ((itv) >= nfull) {          /* wave-uniform branch */         \
            bool _v = _idx < e1;                                         \
            _t.x = _v ? _t.x : 0;     /* masked gathers hit row 0 */     \
            _t.y = _v ? _t.y : 0;     /* zero lap: no contribution */    \
        }                                                                \
        p = _t;                                                          \
    } while (0)
#define BPERM(cc, ll, p) do {                                            \
        cc[0] = __builtin_amdgcn_ds_bpermute(bp0, (p).x);                \
        cc[1] = __builtin_amdgcn_ds_bpermute(bp1, (p).x);                \
        cc[2] = __builtin_amdgcn_ds_bpermute(bp2, (p).x);                \
        cc[3] = __builtin_amdgcn_ds_bpermute(bp3, (p).x);                \
        ll[0] = __builtin_amdgcn_ds_bpermute(bp0, (p).y);                \
        ll[1] = __builtin_amdgcn_ds_bpermute(bp1, (p).y);                \
        ll[2] = __builtin_amdgcn_ds_bpermute(bp2, (p).y);                \
        ll[3] = __builtin_amdgcn_ds_bpermute(bp3, (p).y);                \
    } while (0)
#define GATHER(G, cc) do {                                               \
        _Pragma("unroll")                                                \
        for (int _u = 0; _u < 4; ++_u)                                   \
            G[_u] = *(const uint2*)(xs + ((((unsigned)cc[_u]) << 7) + vs8)); \
    } while (0)
#define CONSUME(G, ll) do {                                              \
        _Pragma("unroll")                                                \
        for (int _u = 0; _u < 4; ++_u) {                                 \
            float _l = __int_as_float(ll[_u]);                           \
            f32x2 _f0 = __builtin_amdgcn_cvt_pk_f32_fp8((int)G[_u].x, false); \
            f32x2 _f1 = __builtin_amdgcn_cvt_pk_f32_fp8((int)G[_u].x, true);  \
            f32x2 _f2 = __builtin_amdgcn_cvt_pk_f32_fp8((int)G[_u].y, false); \
            f32x2 _f3 = __builtin_amdgcn_cvt_pk_f32_fp8((int)G[_u].y, true);  \
            acc0 += _l * _f0.x; acc1 += _l * _f0.y;                      \
            acc2 += _l * _f1.x; acc3 += _l * _f1.y;                      \
            acc4 += _l * _f2.x; acc5 += _l * _f2.y;                      \
            acc6 += _l * _f3.x; acc7 += _l * _f3.y;                      \
        }                                                                \
    } while (0)

        int2 pA, pB;
        int cA[4], cB[4], lA[4], lB[4];
        uint2 GA[4], GB[4];

        LOADEP(pA, 0);
        BPERM(cA, lA, pA);
        GATHER(GA, cA);
        int it = 0;
        while (it + 2 <= niter) {
            LOADEP(pB, it + 1);
            BPERM(cB, lB, pB);
            GATHER(GB, cB);
            CONSUME(GA, lA);
            if (it + 2 < niter) {
                LOADEP(pA, it + 2);
                BPERM(cA, lA, pA);
                GATHER(GA, cA);
            }
            CONSUME(GB, lB);
            it += 2;
        }
        if (it < niter) CONSUME(GA, lA);   // odd leftover (in flight from prologue/loop)
#undef LOADEP
#undef BPERM
#undef GATHER
#undef CONSUME
    }
    // merge the 4 quadrants (channel c held by lanes s, s+16, s+32, s+48)
    acc0 += __shfl(acc0, lane ^ 16, 64); acc1 += __shfl(acc1, lane ^ 16, 64);
    acc2 += __shfl(acc2, lane ^ 16, 64); acc3 += __shfl(acc3, lane ^ 16, 64);
    acc4 += __shfl(acc4, lane ^ 16, 64); acc5 += __shfl(acc5, lane ^ 16, 64);
    acc6 += __shfl(acc6, lane ^ 16, 64); acc7 += __shfl(acc7, lane ^ 16, 64);
    acc0 += __shfl(acc0, lane ^ 32, 64); acc1 += __shfl(acc1, lane ^ 32, 64);
    acc2 += __shfl(acc2, lane ^ 32, 64); acc3 += __shfl(acc3, lane ^ 32, 64);
    acc4 += __shfl(acc4, lane ^ 32, 64); acc5 += __shfl(acc5, lane ^ 32, 64);
    acc6 += __shfl(acc6, lane ^ 32, 64); acc7 += __shfl(acc7, lane ^ 32, 64);
    if (q == 0) {
        float o0 = a * acc0, o1 = a * acc1, o2 = a * acc2, o3 = a * acc3;
        float o4 = a * acc4, o5 = a * acc5, o6 = a * acc6, o7 = a * acc7;
        if (zmode == 1) {
            uint4 zg = *((const uint4*)z + (size_t)r * 16 + s);
            o0 += b * bflo(zg.x); o1 += b * bfhi(zg.x);
            o2 += b * bflo(zg.y); o3 += b * bfhi(zg.y);
            o4 += b * bflo(zg.z); o5 += b * bfhi(zg.z);
            o6 += b * bflo(zg.w); o7 += b * bfhi(zg.w);
        } else if (zmode == 3) {
            const f32x4* zp = (const f32x4*)z + (size_t)r * 32 + s * 2;
            f32x4 z0 = zp[0], z1 = zp[1];
            o0 += b * z0.x; o1 += b * z0.y; o2 += b * z0.z; o3 += b * z0.w;
            o4 += b * z1.x; o5 += b * z1.y; o6 += b * z1.z; o7 += b * z1.w;
        }
        uint4 ob;
        ob.x = (unsigned)f2bf(o0) | ((unsigned)f2bf(o1) << 16);
        ob.y = (unsigned)f2bf(o2) | ((unsigned)f2bf(o3) << 16);
        ob.z = (unsigned)f2bf(o4) | ((unsigned)f2bf(o5) << 16);
        ob.w = (unsigned)f2bf(o6) | ((unsigned)f2bf(o7) << 16);
        *((uint4*)yb + (size_t)r * 16 + s) = ob;
        if (y8) {
            int pk0 = __builtin_amdgcn_cvt_pk_fp8_f32(o0, o1, 0, false);
            pk0 = __builtin_amdgcn_cvt_pk_fp8_f32(o2, o3, pk0, true);
            int pk1 = __builtin_amdgcn_cvt_pk_fp8_f32(o4, o5, 0, false);
            pk1 = __builtin_amdgcn_cvt_pk_fp8_f32(o6, o7, pk1, true);
            *((uint2*)y8 + (size_t)r * 16 + s) = make_uint2((unsigned)pk0, (unsigned)pk1);
        }
    }
}

// ---- A-fragment loader: fmt 0 = bf16, 1 = fp32 (convert, RNE) ----
__device__ __forceinline__ void load_afrags(const void* A, int fmt, int row, int quad,
                                            bf16x8* frag) {
    if (fmt == 0) {
        const short* p = (const short*)A + (size_t)row * 128 + quad * 8;
#pragma unroll
        for (int kk = 0; kk < 4; ++kk) frag[kk] = *(const bf16x8*)(p + kk * 32);
    } else {
        const float* p = (const float*)A + (size_t)row * 128 + quad * 8;
#pragma unroll
        for (int kk = 0; kk < 4; ++kk) {
            f32x4 u = *(const f32x4*)(p + kk * 32);
            f32x4 v = *(const f32x4*)(p + kk * 32 + 4);
            bf16x8 fr;
            fr[0] = (short)f2bf(u.x); fr[1] = (short)f2bf(u.y);
            fr[2] = (short)f2bf(u.z); fr[3] = (short)f2bf(u.w);
            fr[4] = (short)f2bf(v.x); fr[5] = (short)f2bf(v.y);
            fr[6] = (short)f2bf(v.z); fr[7] = (short)f2bf(v.w);
            frag[kk] = fr;
        }
    }
}

// ---- fully-fused MFMA GEMM: out = x@W0 + t1@W1 + t2@W2 + t3@W3 + bias ----
// One pass, mode-0 only (no out read-modify-write). Wave-local LDS-transpose
// epilogue: 8 coalesced dwordx4 stores/thread instead of 32 scattered dwords.
// No __syncthreads: each wave owns its cbuf slice; intra-wave LDS ops are ordered.
__global__ void __launch_bounds__(256) k_gemm4(
    const float* __restrict__ x,
    const unsigned short* __restrict__ t1,
    const unsigned short* __restrict__ t2,
    const unsigned short* __restrict__ t3,
    const unsigned short* __restrict__ wt,   // 4 x [128][128] bf16 (c-major)
    float* __restrict__ out, const float* __restrict__ bias)
{
    __shared__ float cbuf[4][16 * 132];      // 132-dword row pad: write-phase 2-way max
    int wv = threadIdx.x >> 6, lane = threadIdx.x & 63;
    int m = lane & 15, quad = lane >> 4;
    int r0 = blockIdx.x * 64 + wv * 16;
    int row = r0 + m;
    int rowc = (row >= N_NODES) ? (N_NODES - 1) : row;  // clamp fp32 x reads only
    bf16x8 a0[4], a1[4], a2[4], a3[4];
    load_afrags(x,  1, rowc, quad, a0);
    load_afrags(t1, 0, row,  quad, a1);      // t buffers have ROWS_PAD rows
    load_afrags(t2, 0, row,  quad, a2);
    load_afrags(t3, 0, row,  quad, a3);
    float* cw = &cbuf[wv][0];
#pragma unroll
    for (int ct = 0; ct < 8; ++ct) {
        int c0 = ct * 16;
        const short* B0 = (const short*)wt + (c0 + m) * 128 + quad * 8;
        f32x4 accA = {0.f, 0.f, 0.f, 0.f};
        f32x4 accB = {0.f, 0.f, 0.f, 0.f};
#pragma unroll
        for (int kk = 0; kk < 4; ++kk) {
            bf16x8 b0 = *(const bf16x8*)(B0 + kk * 32);
            bf16x8 b1 = *(const bf16x8*)(B0 + 16384 + kk * 32);
            bf16x8 b2 = *(const bf16x8*)(B0 + 32768 + kk * 32);
            bf16x8 b3 = *(const bf16x8*)(B0 + 49152 + kk * 32);
            accA = __builtin_amdgcn_mfma_f32_16x16x32_bf16(a0[kk], b0, accA, 0, 0, 0);
            accB = __builtin_amdgcn_mfma_f32_16x16x32_bf16(a1[kk], b1, accB, 0, 0, 0);
            accA = __builtin_amdgcn_mfma_f32_16x16x32_bf16(a2[kk], b2, accA, 0, 0, 0);
            accB = __builtin_amdgcn_mfma_f32_16x16x32_bf16(a3[kk], b3, accB, 0, 0, 0);
        }
        // C/D layout: col = c0+m, row = quad*4+i -> stash in LDS (row-major, pad 132)
#pragma unroll
        for (int i = 0; i < 4; ++i)
            cw[(quad * 4 + i) * 132 + c0 + m] = accA[i] + accB[i];
    }
    // transpose epilogue: lane covers row er = lane>>2, cols ec..ec+31
    int er = lane >> 2, ec = (lane & 3) * 32;
    int gr = r0 + er;
#pragma unroll
    for (int j = 0; j < 8; ++j) {
        f32x4 v = *(f32x4*)(cw + er * 132 + ec + j * 4);
        f32x4 bb = *(const f32x4*)(bias + ec + j * 4);
        v.x += bb.x; v.y += bb.y; v.z += bb.z; v.w += bb.w;
        if (gr < N_NODES)
            *(f32x4*)(out + (size_t)gr * 128 + ec + j * 4) = v;
    }
}

extern "C" void kernel_launch(void* const* d_in, const int* in_sizes, int n_in,
                              void* d_out, int out_size, void* d_ws, size_t ws_size,
                              hipStream_t stream) {
    const float* x    = (const float*)d_in[0];
    const float* lap  = (const float*)d_in[1];
    const float* w    = (const float*)d_in[2];
    const float* bias = (const float*)d_in[3];
    const int*   ei   = (const int*)d_in[4];
    float* out = (float*)d_out;

    char* ws = (char*)d_ws;
    const size_t SZ_BF = (size_t)ROWS_PAD * 128 * 2;   // 25,608,192 B
    const size_t SZ_F8 = (size_t)ROWS_PAD * 128;       // 12,804,096 B
    const size_t SZ_EP = SZ_BF + 1024;                 // ep + 64 zero pad slots (+ slack)
    // layout (lifetimes annotated):
    int2* ep            = (int2*)(ws);                              // dead after spmm3
    unsigned char* xf8  = (unsigned char*)(ws + SZ_EP);             // dead after SpMM1
    unsigned char* t1_8 = (unsigned char*)(ws + SZ_EP + SZ_F8);     // dead after SpMM2
    unsigned char* t3_b = (unsigned char*)(ws + SZ_EP);             // reuses xf8+t1_8 region (bf16)
    unsigned char* t1_b = (unsigned char*)(ws + SZ_EP + SZ_BF);
    unsigned char* t2_8 = (unsigned char*)(ws + SZ_EP + 2 * SZ_BF);
    unsigned char* t2_b = (unsigned char*)(ws + SZ_EP + 2 * SZ_BF + SZ_F8);
    uint2* ep_tmp       = (uint2*)(ws + SZ_EP + 2 * SZ_BF);         // aliases t2_8 + t2_b head; dead after rsort
    char* p = ws + SZ_EP + 3 * SZ_BF + SZ_F8;
    int* rowstart = (int*)p; p += 400128;
    int* bcnt     = (int*)p; p += 3200;
    int* bbase    = (int*)p; p += 3200;
    int* bcursor  = (int*)p; p += 3200;
    unsigned short* wt = (unsigned short*)p;           // 4*128*128 bf16

    hipMemsetAsync(bcnt, 0, N_BUCKETS * sizeof(int), stream);
    k_convert_x<<<1024, 256, 0, stream>>>(x, (unsigned*)xf8);
    k_convert_w<<<256, 256, 0, stream>>>(w, wt);
    k_bhist<<<(N_EDGES + 8191) / 8192, 256, 0, stream>>>(ei, bcnt);
    k_bscan<<<1, 1024, 0, stream>>>(bcnt, bbase, bcursor, rowstart, ep);
    k_bin<<<(N_EDGES + 16383) / 16384, 1024, 0, stream>>>(ei, lap, bcursor, ep_tmp);
    k_rsort<<<N_BUCKETS, 256, 0, stream>>>(ep_tmp, bbase, rowstart, ep);

    // Tx1 = L x            (gather fp8 x; write bf16 + fp8)
    k_spmm8<<<ROWS_PAD / 4, 256, 0, stream>>>(xf8, nullptr, 0,
        (unsigned*)t1_8, (uint2*)t1_b, rowstart, ep, 1.f, 0.f);
    // Tx2 = 2 L Tx1 - x    (gather fp8 Tx1; z fp32 x; write bf16 + fp8)
    k_spmm8<<<ROWS_PAD / 4, 256, 0, stream>>>(t1_8, x, 3,
        (unsigned*)t2_8, (uint2*)t2_b, rowstart, ep, 2.f, -1.f);
    // Tx3 = 2 L Tx2 - Tx1  (gather fp8 Tx2; z bf16 Tx1; write bf16 only, into dead xf8/t1_8 region)
    k_spmm8<<<ROWS_PAD / 4, 256, 0, stream>>>(t2_8, t1_b, 1,
        nullptr, (uint2*)t3_b, rowstart, ep, 2.f, -1.f);
    // out = x@W0 + Tx1@W1 + Tx2@W2 + Tx3@W3 + bias   (single fused GEMM, no RMW)
    k_gemm4<<<ROWS_PAD / 64, 256, 0, stream>>>(x, (const unsigned short*)t1_b,
        (const unsigned short*)t2_b, (const unsigned short*)t3_b, wt, out, bias);
}

// Round 6
// 575.000 us; speedup vs baseline: 1.0076x; 1.0076x over previous
//
#include <hip/hip_runtime.h>

#define N_NODES 100000
#define N_EDGES 3200000
#define ROWS_PAD 100032   // multiple of 64 for GEMM tiling
#define N_BUCKETS 782     // ceil(100000/128)
#define BUCKET_SHIFT 7

typedef __attribute__((ext_vector_type(8))) short bf16x8;
typedef __attribute__((ext_vector_type(4))) float f32x4;
typedef __attribute__((ext_vector_type(2))) float f32x2;

__device__ __forceinline__ unsigned short f2bf(float f) {
    unsigned u = __float_as_uint(f);
    unsigned r = (u + 0x7fffu + ((u >> 16) & 1u)) >> 16;  // round-to-nearest-even
    return (unsigned short)r;
}
__device__ __forceinline__ float bflo(unsigned u) { return __uint_as_float(u << 16); }
__device__ __forceinline__ float bfhi(unsigned u) { return __uint_as_float(u & 0xffff0000u); }

// ---- convert x fp32 -> fp8 e4m3 [ROWS_PAD,128]; persistent grid-stride, 16B/thread/iter ----
__global__ void __launch_bounds__(256) k_convert_x(const float* __restrict__ x,
                                                   unsigned* __restrict__ xf8) {
    const int QTOT = ROWS_PAD * 32;            // 4-channel quads
    for (int q = blockIdx.x * 256 + threadIdx.x; q < QTOT; q += 1024 * 256) {
        int r = q >> 5;
        f32x4 f = {0.f, 0.f, 0.f, 0.f};
        if (r < N_NODES) f = *(const f32x4*)(x + 4 * (size_t)q);
        int pk = __builtin_amdgcn_cvt_pk_fp8_f32(f.x, f.y, 0, false);
        pk = __builtin_amdgcn_cvt_pk_fp8_f32(f.z, f.w, pk, true);
        xf8[q] = (unsigned)pk;
    }
}

// ---- convert+transpose W [4][k][c] fp32 -> WT [4][c][k] bf16 ----
__global__ void k_convert_w(const float* __restrict__ w, unsigned short* __restrict__ wt) {
    int i = blockIdx.x * 256 + threadIdx.x;          // 65536 total
    int m = i >> 14, rem = i & 16383, k = rem >> 7, c = rem & 127;
    wt[(m << 14) + (c << 7) + k] = f2bf(w[i]);
}

// ---- coarse bucket histogram (row>>7), LDS-aggregated ----
__global__ void __launch_bounds__(256) k_bhist(const int* __restrict__ ei, int* __restrict__ bcnt) {
    __shared__ int h[N_BUCKETS];
    for (int i = threadIdx.x; i < N_BUCKETS; i += 256) h[i] = 0;
    __syncthreads();
    int base = blockIdx.x * 8192;
#pragma unroll
    for (int i = 0; i < 32; ++i) {
        int e = base + threadIdx.x + i * 256;
        if (e < N_EDGES) atomicAdd(&h[ei[e] >> BUCKET_SHIFT], 1);
    }
    __syncthreads();
    for (int i = threadIdx.x; i < N_BUCKETS; i += 256)
        if (h[i]) atomicAdd(&bcnt[i], h[i]);
}

// ---- one-block exclusive scan of bucket counts; also zero ep's 64 pad slots past E ----
__global__ void __launch_bounds__(1024) k_bscan(const int* __restrict__ bcnt,
                                                int* __restrict__ bbase,
                                                int* __restrict__ bcursor,
                                                int* __restrict__ rowstart,
                                                int2* __restrict__ ep) {
    __shared__ int s[1024];
    int t = threadIdx.x;
    int v = (t < N_BUCKETS) ? bcnt[t] : 0;
    s[t] = v;
    __syncthreads();
    for (int off = 1; off < 1024; off <<= 1) {
        int tv = (t >= off) ? s[t - off] : 0;
        __syncthreads();
        s[t] += tv;
        __syncthreads();
    }
    if (t < N_BUCKETS) {
        int ex = s[t] - v;
        bbase[t] = ex;
        bcursor[t] = ex;
    }
    if (t == 0) {
        bbase[N_BUCKETS] = N_EDGES;
        rowstart[N_NODES] = N_EDGES;
    }
    // zero pad entries so the masked tail batch can over-read valid memory
    if (t < 64) ep[N_EDGES + t] = make_int2(0, 0);
}

// ---- pass 1: bin edges by coarse bucket; per-block run reservation -> L2-local scatter ----
__global__ void __launch_bounds__(1024) k_bin(const int* __restrict__ ei,
                                              const float* __restrict__ lap,
                                              int* __restrict__ bcursor,
                                              uint2* __restrict__ ep_tmp) {
    __shared__ int h[N_BUCKETS];
    __shared__ int runbase[N_BUCKETS];
    for (int i = threadIdx.x; i < N_BUCKETS; i += 1024) h[i] = 0;
    __syncthreads();
    int base = blockIdx.x * 16384;
#pragma unroll
    for (int i = 0; i < 16; ++i) {
        int e = base + threadIdx.x + i * 1024;
        if (e < N_EDGES) atomicAdd(&h[ei[e] >> BUCKET_SHIFT], 1);
    }
    __syncthreads();
    for (int i = threadIdx.x; i < N_BUCKETS; i += 1024) {
        int c = h[i];
        runbase[i] = c ? atomicAdd(&bcursor[i], c) : 0;
        h[i] = 0;   // reuse as local cursor
    }
    __syncthreads();
#pragma unroll
    for (int i = 0; i < 16; ++i) {
        int e = base + threadIdx.x + i * 1024;
        if (e < N_EDGES) {
            int row = ei[e], col = ei[N_EDGES + e];
            int b = row >> BUCKET_SHIFT;
            int p = runbase[b] + atomicAdd(&h[b], 1);
            ep_tmp[p] = make_uint2(((unsigned)(row & 127) << 17) | (unsigned)col,
                                   __float_as_uint(lap[e]));
        }
    }
}

// ---- pass 2: per-bucket row sort in LDS; emit rowstart + final ep ----
#define ST_CAP 5120
__global__ void __launch_bounds__(256) k_rsort(const uint2* __restrict__ ep_tmp,
                                               const int* __restrict__ bbase,
                                               int* __restrict__ rowstart,
                                               int2* __restrict__ ep) {
    __shared__ uint2 st[ST_CAP];
    __shared__ int h[128];
    __shared__ int lcur[128];
    int b = blockIdx.x;
    int base = bbase[b], end = bbase[b + 1];
    int n = end - base;
    if (n > ST_CAP) n = ST_CAP;   // statistically unreachable
    for (int i = threadIdx.x; i < n; i += 256) st[i] = ep_tmp[base + i];
    if (threadIdx.x < 128) h[threadIdx.x] = 0;
    __syncthreads();
    for (int i = threadIdx.x; i < n; i += 256) atomicAdd(&h[st[i].x >> 17], 1);
    __syncthreads();
    int t = threadIdx.x;
    int v = (t < 128) ? h[t] : 0;
    for (int off = 1; off < 128; off <<= 1) {
        int tv = (t < 128 && t >= off) ? h[t - off] : 0;
        __syncthreads();
        if (t < 128) h[t] += tv;
        __syncthreads();
    }
    if (t < 128) {
        int ex = h[t] - v;
        int r = (b << BUCKET_SHIFT) + t;
        if (r < N_NODES) rowstart[r] = base + ex;
        lcur[t] = base + ex;
    }
    __syncthreads();
    for (int i = threadIdx.x; i < n; i += 256) {
        uint2 s = st[i];
        int r = s.x >> 17;
        int p = atomicAdd(&lcur[r], 1);
        ep[p] = make_int2((int)(s.x & 0x1FFFFu), (int)s.y);
    }
}

// ---- SpMM gather (fp8 source), QUADRANT edition ----
// TA lane-address minimization: 16-lane dwordx2 gathers (4 edges/instr), one
// per-lane ep load per 16 edges + ds_bpermute distribution (LDS pipe).
// zmode: 0 = none, 1 = bf16 z, 3 = fp32 z.
__global__ void __launch_bounds__(256) k_spmm8(
    const unsigned char* __restrict__ xs, const void* __restrict__ z, int zmode,
    unsigned* __restrict__ y8, uint2* __restrict__ yb,
    const int* __restrict__ rowstart, const int2* __restrict__ ep, float a, float b)
{
    int wv = threadIdx.x >> 6, lane = threadIdx.x & 63;
    int r = blockIdx.x * 4 + wv;
    if (r >= N_NODES) return;    // pad rows never stored to out (masked in GEMM)
    int q = lane >> 4, s = lane & 15;
    unsigned vs8 = (unsigned)s * 8u;
    // bpermute byte-addrs: round u pulls from source lane u*4+q
    int bp0 = (q) * 4, bp1 = (4 + q) * 4, bp2 = (8 + q) * 4, bp3 = (12 + q) * 4;
    float acc0 = 0.f, acc1 = 0.f, acc2 = 0.f, acc3 = 0.f;
    float acc4 = 0.f, acc5 = 0.f, acc6 = 0.f, acc7 = 0.f;
    int e0 = rowstart[r], e1 = rowstart[r + 1];
    int cnt = e1 - e0;
    if (cnt > 0) {
        int niter = (cnt + 15) >> 4;      // 16 edges per stage
        int nfull = cnt >> 4;             // stages with no out-of-range slot
        const char* epb = (const char*)ep;

#define LOADEP(p, itv) do {                                              \
        int _idx = e0 + (itv) * 16 + s;                                  \
        int2 _t = *(const int2*)(epb + (unsigned)_idx * 8u);             \
        if ((itv) >= nfull) {          /* wave-uniform branch */         \
            bool _v = _idx < e1;                                         \
            _t.x = _v ? _t.x : 0;     /* masked gathers hit row 0 */     \
            _t.y = _v ? _t.y : 0;     /* zero lap: no contribution */    \
        }                                                                \
        p = _t;                                                          \
    } while (0)
#define BPERM(cc, ll, p) do {                                            \
        cc[0] = __builtin_amdgcn_ds_bpermute(bp0, (p).x);                \
        cc[1] = __builtin_amdgcn_ds_bpermute(bp1, (p).x);                \
        cc[2] = __builtin_amdgcn_ds_bpermute(bp2, (p).x);                \
        cc[3] = __builtin_amdgcn_ds_bpermute(bp3, (p).x);                \
        ll[0] = __builtin_amdgcn_ds_bpermute(bp0, (p).y);                \
        ll[1] = __builtin_amdgcn_ds_bpermute(bp1, (p).y);                \
        ll[2] = __builtin_amdgcn_ds_bpermute(bp2, (p).y);                \
        ll[3] = __builtin_amdgcn_ds_bpermute(bp3, (p).y);                \
    } while (0)
#define GATHER(G, cc) do {                                               \
        _Pragma("unroll")                                                \
        for (int _u = 0; _u < 4; ++_u)                                   \
            G[_u] = *(const uint2*)(xs + ((((unsigned)cc[_u]) << 7) + vs8)); \
    } while (0)
#define CONSUME(G, ll) do {                                              \
        _Pragma("unroll")                                                \
        for (int _u = 0; _u < 4; ++_u) {                                 \
            float _l = __int_as_float(ll[_u]);                           \
            f32x2 _f0 = __builtin_amdgcn_cvt_pk_f32_fp8((int)G[_u].x, false); \
            f32x2 _f1 = __builtin_amdgcn_cvt_pk_f32_fp8((int)G[_u].x, true);  \
            f32x2 _f2 = __builtin_amdgcn_cvt_pk_f32_fp8((int)G[_u].y, false); \
            f32x2 _f3 = __builtin_amdgcn_cvt_pk_f32_fp8((int)G[_u].y, true);  \
            acc0 += _l * _f0.x; acc1 += _l * _f0.y;                      \
            acc2 += _l * _f1.x; acc3 += _l * _f1.y;                      \
            acc4 += _l * _f2.x; acc5 += _l * _f2.y;                      \
            acc6 += _l * _f3.x; acc7 += _l * _f3.y;                      \
        }                                                                \
    } while (0)

        int2 pA, pB;
        int cA[4], cB[4], lA[4], lB[4];
        uint2 GA[4], GB[4];

        LOADEP(pA, 0);
        BPERM(cA, lA, pA);
        GATHER(GA, cA);
        int it = 0;
        while (it + 2 <= niter) {
            LOADEP(pB, it + 1);
            BPERM(cB, lB, pB);
            GATHER(GB, cB);
            CONSUME(GA, lA);
            if (it + 2 < niter) {
                LOADEP(pA, it + 2);
                BPERM(cA, lA, pA);
                GATHER(GA, cA);
            }
            CONSUME(GB, lB);
            it += 2;
        }
        if (it < niter) CONSUME(GA, lA);   // odd leftover (in flight from prologue/loop)
#undef LOADEP
#undef BPERM
#undef GATHER
#undef CONSUME
    }
    // merge the 4 quadrants (channel c held by lanes s, s+16, s+32, s+48)
    acc0 += __shfl(acc0, lane ^ 16, 64); acc1 += __shfl(acc1, lane ^ 16, 64);
    acc2 += __shfl(acc2, lane ^ 16, 64); acc3 += __shfl(acc3, lane ^ 16, 64);
    acc4 += __shfl(acc4, lane ^ 16, 64); acc5 += __shfl(acc5, lane ^ 16, 64);
    acc6 += __shfl(acc6, lane ^ 16, 64); acc7 += __shfl(acc7, lane ^ 16, 64);
    acc0 += __shfl(acc0, lane ^ 32, 64); acc1 += __shfl(acc1, lane ^ 32, 64);
    acc2 += __shfl(acc2, lane ^ 32, 64); acc3 += __shfl(acc3, lane ^ 32, 64);
    acc4 += __shfl(acc4, lane ^ 32, 64); acc5 += __shfl(acc5, lane ^ 32, 64);
    acc6 += __shfl(acc6, lane ^ 32, 64); acc7 += __shfl(acc7, lane ^ 32, 64);
    if (q == 0) {
        float o0 = a * acc0, o1 = a * acc1, o2 = a * acc2, o3 = a * acc3;
        float o4 = a * acc4, o5 = a * acc5, o6 = a * acc6, o7 = a * acc7;
        if (zmode == 1) {
            uint4 zg = *((const uint4*)z + (size_t)r * 16 + s);
            o0 += b * bflo(zg.x); o1 += b * bfhi(zg.x);
            o2 += b * bflo(zg.y); o3 += b * bfhi(zg.y);
            o4 += b * bflo(zg.z); o5 += b * bfhi(zg.z);
            o6 += b * bflo(zg.w); o7 += b * bfhi(zg.w);
        } else if (zmode == 3) {
            const f32x4* zp = (const f32x4*)z + (size_t)r * 32 + s * 2;
            f32x4 z0 = zp[0], z1 = zp[1];
            o0 += b * z0.x; o1 += b * z0.y; o2 += b * z0.z; o3 += b * z0.w;
            o4 += b * z1.x; o5 += b * z1.y; o6 += b * z1.z; o7 += b * z1.w;
        }
        uint4 ob;
        ob.x = (unsigned)f2bf(o0) | ((unsigned)f2bf(o1) << 16);
        ob.y = (unsigned)f2bf(o2) | ((unsigned)f2bf(o3) << 16);
        ob.z = (unsigned)f2bf(o4) | ((unsigned)f2bf(o5) << 16);
        ob.w = (unsigned)f2bf(o6) | ((unsigned)f2bf(o7) << 16);
        *((uint4*)yb + (size_t)r * 16 + s) = ob;
        if (y8) {
            int pk0 = __builtin_amdgcn_cvt_pk_fp8_f32(o0, o1, 0, false);
            pk0 = __builtin_amdgcn_cvt_pk_fp8_f32(o2, o3, pk0, true);
            int pk1 = __builtin_amdgcn_cvt_pk_fp8_f32(o4, o5, 0, false);
            pk1 = __builtin_amdgcn_cvt_pk_fp8_f32(o6, o7, pk1, true);
            *((uint2*)y8 + (size_t)r * 16 + s) = make_uint2((unsigned)pk0, (unsigned)pk1);
        }
    }
}

// ---- fully-fused MFMA GEMM: out = x@W0 + t1@W1 + t2@W2 + t3@W3 + bias ----
// v2: terms-outer / ct-inner with persistent acc[8]. Live registers per term:
// 32 acc + 16 A-frag + B staging -- fits comfortably in 128 VGPRs
// (__launch_bounds__(256,4)), so A is loaded from HBM exactly ONCE per term
// (round-5 version had VGPR=68 < the 64 needed for 4 A-frag sets -> compiler
// rematerialized A loads per ct iteration and serialized B loads = 138 us
// latency-bound). Wave-local LDS-transpose epilogue: 8 coalesced dwordx4
// stores/thread; no __syncthreads (per-wave cbuf slice, intra-wave LDS ordered).
__global__ void __launch_bounds__(256, 4) k_gemm4(
    const float* __restrict__ x,
    const unsigned short* __restrict__ t1,
    const unsigned short* __restrict__ t2,
    const unsigned short* __restrict__ t3,
    const unsigned short* __restrict__ wt,   // 4 x [128][128] bf16 (c-major)
    float* __restrict__ out, const float* __restrict__ bias)
{
    __shared__ float cbuf[4][16 * 132];      // 132-dword row pad
    int wv = threadIdx.x >> 6, lane = threadIdx.x & 63;
    int m = lane & 15, quad = lane >> 4;
    int r0 = blockIdx.x * 64 + wv * 16;
    int row = r0 + m;
    int rowc = (row >= N_NODES) ? (N_NODES - 1) : row;  // clamp fp32 x reads only

    f32x4 acc[8];
#pragma unroll
    for (int ct = 0; ct < 8; ++ct) acc[ct] = (f32x4){0.f, 0.f, 0.f, 0.f};

    // term 0: x (fp32 -> bf16 on the fly)
    {
        bf16x8 a[4];
        {
            const float* p = x + (size_t)rowc * 128 + quad * 8;
#pragma unroll
            for (int kk = 0; kk < 4; ++kk) {
                f32x4 u = *(const f32x4*)(p + kk * 32);
                f32x4 v = *(const f32x4*)(p + kk * 32 + 4);
                bf16x8 fr;
                fr[0] = (short)f2bf(u.x); fr[1] = (short)f2bf(u.y);
                fr[2] = (short)f2bf(u.z); fr[3] = (short)f2bf(u.w);
                fr[4] = (short)f2bf(v.x); fr[5] = (short)f2bf(v.y);
                fr[6] = (short)f2bf(v.z); fr[7] = (short)f2bf(v.w);
                a[kk] = fr;
            }
        }
#pragma unroll
        for (int ct = 0; ct < 8; ++ct) {
            const short* B = (const short*)wt + (ct * 16 + m) * 128 + quad * 8;
#pragma unroll
            for (int kk = 0; kk < 4; ++kk)
                acc[ct] = __builtin_amdgcn_mfma_f32_16x16x32_bf16(
                    a[kk], *(const bf16x8*)(B + kk * 32), acc[ct], 0, 0, 0);
        }
    }
    // terms 1..3: bf16 A
    const unsigned short* tA[3] = {t1, t2, t3};
#pragma unroll
    for (int t = 0; t < 3; ++t) {
        bf16x8 a[4];
        {
            const short* p = (const short*)tA[t] + (size_t)row * 128 + quad * 8;
#pragma unroll
            for (int kk = 0; kk < 4; ++kk) a[kk] = *(const bf16x8*)(p + kk * 32);
        }
        const short* Wb = (const short*)wt + (t + 1) * 16384;
#pragma unroll
        for (int ct = 0; ct < 8; ++ct) {
            const short* B = Wb + (ct * 16 + m) * 128 + quad * 8;
#pragma unroll
            for (int kk = 0; kk < 4; ++kk)
                acc[ct] = __builtin_amdgcn_mfma_f32_16x16x32_bf16(
                    a[kk], *(const bf16x8*)(B + kk * 32), acc[ct], 0, 0, 0);
        }
    }
    // stash C in LDS (C/D layout: col = ct*16+m, row = quad*4+i)
    float* cw = &cbuf[wv][0];
#pragma unroll
    for (int ct = 0; ct < 8; ++ct)
#pragma unroll
        for (int i = 0; i < 4; ++i)
            cw[(quad * 4 + i) * 132 + ct * 16 + m] = acc[ct][i];
    // transpose epilogue: lane covers row er = lane>>2, cols ec..ec+31
    int er = lane >> 2, ec = (lane & 3) * 32;
    int gr = r0 + er;
#pragma unroll
    for (int j = 0; j < 8; ++j) {
        f32x4 v = *(f32x4*)(cw + er * 132 + ec + j * 4);
        f32x4 bb = *(const f32x4*)(bias + ec + j * 4);
        v.x += bb.x; v.y += bb.y; v.z += bb.z; v.w += bb.w;
        if (gr < N_NODES)
            *(f32x4*)(out + (size_t)gr * 128 + ec + j * 4) = v;
    }
}

extern "C" void kernel_launch(void* const* d_in, const int* in_sizes, int n_in,
                              void* d_out, int out_size, void* d_ws, size_t ws_size,
                              hipStream_t stream) {
    const float* x    = (const float*)d_in[0];
    const float* lap  = (const float*)d_in[1];
    const float* w    = (const float*)d_in[2];
    const float* bias = (const float*)d_in[3];
    const int*   ei   = (const int*)d_in[4];
    float* out = (float*)d_out;

    char* ws = (char*)d_ws;
    const size_t SZ_BF = (size_t)ROWS_PAD * 128 * 2;   // 25,608,192 B
    const size_t SZ_F8 = (size_t)ROWS_PAD * 128;       // 12,804,096 B
    const size_t SZ_EP = SZ_BF + 1024;                 // ep + 64 zero pad slots (+ slack)
    // layout (lifetimes annotated):
    int2* ep            = (int2*)(ws);                              // dead after spmm3
    unsigned char* xf8  = (unsigned char*)(ws + SZ_EP);             // dead after SpMM1
    unsigned char* t1_8 = (unsigned char*)(ws + SZ_EP + SZ_F8);     // dead after SpMM2
    unsigned char* t3_b = (unsigned char*)(ws + SZ_EP);             // reuses xf8+t1_8 region (bf16)
    unsigned char* t1_b = (unsigned char*)(ws + SZ_EP + SZ_BF);
    unsigned char* t2_8 = (unsigned char*)(ws + SZ_EP + 2 * SZ_BF);
    unsigned char* t2_b = (unsigned char*)(ws + SZ_EP + 2 * SZ_BF + SZ_F8);
    uint2* ep_tmp       = (uint2*)(ws + SZ_EP + 2 * SZ_BF);         // aliases t2_8 + t2_b head; dead after rsort
    char* p = ws + SZ_EP + 3 * SZ_BF + SZ_F8;
    int* rowstart = (int*)p; p += 400128;
    int* bcnt     = (int*)p; p += 3200;
    int* bbase    = (int*)p; p += 3200;
    int* bcursor  = (int*)p; p += 3200;
    unsigned short* wt = (unsigned short*)p;           // 4*128*128 bf16

    hipMemsetAsync(bcnt, 0, N_BUCKETS * sizeof(int), stream);
    k_convert_x<<<1024, 256, 0, stream>>>(x, (unsigned*)xf8);
    k_convert_w<<<256, 256, 0, stream>>>(w, wt);
    k_bhist<<<(N_EDGES + 8191) / 8192, 256, 0, stream>>>(ei, bcnt);
    k_bscan<<<1, 1024, 0, stream>>>(bcnt, bbase, bcursor, rowstart, ep);
    k_bin<<<(N_EDGES + 16383) / 16384, 1024, 0, stream>>>(ei, lap, bcursor, ep_tmp);
    k_rsort<<<N_BUCKETS, 256, 0, stream>>>(ep_tmp, bbase, rowstart, ep);

    // Tx1 = L x            (gather fp8 x; write bf16 + fp8)
    k_spmm8<<<ROWS_PAD / 4, 256, 0, stream>>>(xf8, nullptr, 0,
        (unsigned*)t1_8, (uint2*)t1_b, rowstart, ep, 1.f, 0.f);
    // Tx2 = 2 L Tx1 - x    (gather fp8 Tx1; z fp32 x; write bf16 + fp8)
    k_spmm8<<<ROWS_PAD / 4, 256, 0, stream>>>(t1_8, x, 3,
        (unsigned*)t2_8, (uint2*)t2_b, rowstart, ep, 2.f, -1.f);
    // Tx3 = 2 L Tx2 - Tx1  (gather fp8 Tx2; z bf16 Tx1; write bf16 only, into dead xf8/t1_8 region)
    k_spmm8<<<ROWS_PAD / 4, 256, 0, stream>>>(t2_8, t1_b, 1,
        nullptr, (uint2*)t3_b, rowstart, ep, 2.f, -1.f);
    // out = x@W0 + Tx1@W1 + Tx2@W2 + Tx3@W3 + bias   (single fused GEMM, no RMW)
    k_gemm4<<<ROWS_PAD / 64, 256, 0, stream>>>(x, (const unsigned short*)t1_b,
        (const unsigned short*)t2_b, (const unsigned short*)t3_b, wt, out, bias);
}

// Round 7
// 501.957 us; speedup vs baseline: 1.1543x; 1.1455x over previous
//
#include <hip/hip_runtime.h>

#define N_NODES 100000
#define N_EDGES 3200000
#define ROWS_PAD 100032   // multiple of 64 for GEMM tiling
#define N_BUCKETS 782     // ceil(100000/128)
#define BUCKET_SHIFT 7

typedef __attribute__((ext_vector_type(8))) short bf16x8;
typedef __attribute__((ext_vector_type(4))) float f32x4;
typedef __attribute__((ext_vector_type(2))) float f32x2;

__device__ __forceinline__ unsigned short f2bf(float f) {
    unsigned u = __float_as_uint(f);
    unsigned r = (u + 0x7fffu + ((u >> 16) & 1u)) >> 16;  // round-to-nearest-even
    return (unsigned short)r;
}
__device__ __forceinline__ float bflo(unsigned u) { return __uint_as_float(u << 16); }
__device__ __forceinline__ float bfhi(unsigned u) { return __uint_as_float(u & 0xffff0000u); }

// ---- convert x fp32 -> fp8 e4m3 [ROWS_PAD,128]; persistent grid-stride, 16B/thread/iter ----
__global__ void __launch_bounds__(256) k_convert_x(const float* __restrict__ x,
                                                   unsigned* __restrict__ xf8) {
    const int QTOT = ROWS_PAD * 32;            // 4-channel quads
    for (int q = blockIdx.x * 256 + threadIdx.x; q < QTOT; q += 1024 * 256) {
        int r = q >> 5;
        f32x4 f = {0.f, 0.f, 0.f, 0.f};
        if (r < N_NODES) f = *(const f32x4*)(x + 4 * (size_t)q);
        int pk = __builtin_amdgcn_cvt_pk_fp8_f32(f.x, f.y, 0, false);
        pk = __builtin_amdgcn_cvt_pk_fp8_f32(f.z, f.w, pk, true);
        xf8[q] = (unsigned)pk;
    }
}

// ---- convert+transpose W [4][k][c] fp32 -> WT [4][c][k] bf16 ----
__global__ void k_convert_w(const float* __restrict__ w, unsigned short* __restrict__ wt) {
    int i = blockIdx.x * 256 + threadIdx.x;          // 65536 total
    int m = i >> 14, rem = i & 16383, k = rem >> 7, c = rem & 127;
    wt[(m << 14) + (c << 7) + k] = f2bf(w[i]);
}

// ---- coarse bucket histogram (row>>7), LDS-aggregated ----
__global__ void __launch_bounds__(256) k_bhist(const int* __restrict__ ei, int* __restrict__ bcnt) {
    __shared__ int h[N_BUCKETS];
    for (int i = threadIdx.x; i < N_BUCKETS; i += 256) h[i] = 0;
    __syncthreads();
    int base = blockIdx.x * 8192;
#pragma unroll
    for (int i = 0; i < 32; ++i) {
        int e = base + threadIdx.x + i * 256;
        if (e < N_EDGES) atomicAdd(&h[ei[e] >> BUCKET_SHIFT], 1);
    }
    __syncthreads();
    for (int i = threadIdx.x; i < N_BUCKETS; i += 256)
        if (h[i]) atomicAdd(&bcnt[i], h[i]);
}

// ---- one-block exclusive scan of bucket counts; also zero ep's 64 pad slots past E ----
__global__ void __launch_bounds__(1024) k_bscan(const int* __restrict__ bcnt,
                                                int* __restrict__ bbase,
                                                int* __restrict__ bcursor,
                                                int* __restrict__ rowstart,
                                                int2* __restrict__ ep) {
    __shared__ int s[1024];
    int t = threadIdx.x;
    int v = (t < N_BUCKETS) ? bcnt[t] : 0;
    s[t] = v;
    __syncthreads();
    for (int off = 1; off < 1024; off <<= 1) {
        int tv = (t >= off) ? s[t - off] : 0;
        __syncthreads();
        s[t] += tv;
        __syncthreads();
    }
    if (t < N_BUCKETS) {
        int ex = s[t] - v;
        bbase[t] = ex;
        bcursor[t] = ex;
    }
    if (t == 0) {
        bbase[N_BUCKETS] = N_EDGES;
        rowstart[N_NODES] = N_EDGES;
    }
    // zero pad entries so the masked tail batch can over-read valid memory
    if (t < 64) ep[N_EDGES + t] = make_int2(0, 0);
}

// ---- pass 1: bin edges by coarse bucket; per-block run reservation -> L2-local scatter ----
__global__ void __launch_bounds__(1024) k_bin(const int* __restrict__ ei,
                                              const float* __restrict__ lap,
                                              int* __restrict__ bcursor,
                                              uint2* __restrict__ ep_tmp) {
    __shared__ int h[N_BUCKETS];
    __shared__ int runbase[N_BUCKETS];
    for (int i = threadIdx.x; i < N_BUCKETS; i += 1024) h[i] = 0;
    __syncthreads();
    int base = blockIdx.x * 16384;
#pragma unroll
    for (int i = 0; i < 16; ++i) {
        int e = base + threadIdx.x + i * 1024;
        if (e < N_EDGES) atomicAdd(&h[ei[e] >> BUCKET_SHIFT], 1);
    }
    __syncthreads();
    for (int i = threadIdx.x; i < N_BUCKETS; i += 1024) {
        int c = h[i];
        runbase[i] = c ? atomicAdd(&bcursor[i], c) : 0;
        h[i] = 0;   // reuse as local cursor
    }
    __syncthreads();
#pragma unroll
    for (int i = 0; i < 16; ++i) {
        int e = base + threadIdx.x + i * 1024;
        if (e < N_EDGES) {
            int row = ei[e], col = ei[N_EDGES + e];
            int b = row >> BUCKET_SHIFT;
            int p = runbase[b] + atomicAdd(&h[b], 1);
            ep_tmp[p] = make_uint2(((unsigned)(row & 127) << 17) | (unsigned)col,
                                   __float_as_uint(lap[e]));
        }
    }
}

// ---- pass 2: per-bucket row sort in LDS; emit rowstart + final ep ----
#define ST_CAP 5120
__global__ void __launch_bounds__(256) k_rsort(const uint2* __restrict__ ep_tmp,
                                               const int* __restrict__ bbase,
                                               int* __restrict__ rowstart,
                                               int2* __restrict__ ep) {
    __shared__ uint2 st[ST_CAP];
    __shared__ int h[128];
    __shared__ int lcur[128];
    int b = blockIdx.x;
    int base = bbase[b], end = bbase[b + 1];
    int n = end - base;
    if (n > ST_CAP) n = ST_CAP;   // statistically unreachable
    for (int i = threadIdx.x; i < n; i += 256) st[i] = ep_tmp[base + i];
    if (threadIdx.x < 128) h[threadIdx.x] = 0;
    __syncthreads();
    for (int i = threadIdx.x; i < n; i += 256) atomicAdd(&h[st[i].x >> 17], 1);
    __syncthreads();
    int t = threadIdx.x;
    int v = (t < 128) ? h[t] : 0;
    for (int off = 1; off < 128; off <<= 1) {
        int tv = (t < 128 && t >= off) ? h[t - off] : 0;
        __syncthreads();
        if (t < 128) h[t] += tv;
        __syncthreads();
    }
    if (t < 128) {
        int ex = h[t] - v;
        int r = (b << BUCKET_SHIFT) + t;
        if (r < N_NODES) rowstart[r] = base + ex;
        lcur[t] = base + ex;
    }
    __syncthreads();
    for (int i = threadIdx.x; i < n; i += 256) {
        uint2 s = st[i];
        int r = s.x >> 17;
        int p = atomicAdd(&lcur[r], 1);
        ep[p] = make_int2((int)(s.x & 0x1FFFFu), (int)s.y);
    }
}

// ---- SpMM gather (fp8 source), QUADRANT edition ----
// TA lane-address minimization: 16-lane dwordx2 gathers (4 edges/instr), one
// per-lane ep load per 16 edges + ds_bpermute distribution (LDS pipe).
// zmode: 0 = none, 1 = bf16 z, 3 = fp32 z.
__global__ void __launch_bounds__(256) k_spmm8(
    const unsigned char* __restrict__ xs, const void* __restrict__ z, int zmode,
    unsigned* __restrict__ y8, uint2* __restrict__ yb,
    const int* __restrict__ rowstart, const int2* __restrict__ ep, float a, float b)
{
    int wv = threadIdx.x >> 6, lane = threadIdx.x & 63;
    int r = blockIdx.x * 4 + wv;
    if (r >= N_NODES) return;    // pad rows never stored to out (masked in GEMM)
    int q = lane >> 4, s = lane & 15;
    unsigned vs8 = (unsigned)s * 8u;
    // bpermute byte-addrs: round u pulls from source lane u*4+q
    int bp0 = (q) * 4, bp1 = (4 + q) * 4, bp2 = (8 + q) * 4, bp3 = (12 + q) * 4;
    float acc0 = 0.f, acc1 = 0.f, acc2 = 0.f, acc3 = 0.f;
    float acc4 = 0.f, acc5 = 0.f, acc6 = 0.f, acc7 = 0.f;
    int e0 = rowstart[r], e1 = rowstart[r + 1];
    int cnt = e1 - e0;
    if (cnt > 0) {
        int niter = (cnt + 15) >> 4;      // 16 edges per stage
        int nfull = cnt >> 4;             // stages with no out-of-range slot
        const char* epb = (const char*)ep;

#define LOADEP(p, itv) do {                                              \
        int _idx = e0 + (itv) * 16 + s;                                  \
        int2 _t = *(const int2*)(epb + (unsigned)_idx * 8u);             \
        if ((itv) >= nfull) {          /* wave-uniform branch */         \
            bool _v = _idx < e1;                                         \
            _t.x = _v ? _t.x : 0;     /* masked gathers hit row 0 */     \
            _t.y = _v ? _t.y : 0;     /* zero lap: no contribution */    \
        }                                                                \
        p = _t;                                                          \
    } while (0)
#define BPERM(cc, ll, p) do {                                            \
        cc[0] = __builtin_amdgcn_ds_bpermute(bp0, (p).x);                \
        cc[1] = __builtin_amdgcn_ds_bpermute(bp1, (p).x);                \
        cc[2] = __builtin_amdgcn_ds_bpermute(bp2, (p).x);                \
        cc[3] = __builtin_amdgcn_ds_bpermute(bp3, (p).x);                \
        ll[0] = __builtin_amdgcn_ds_bpermute(bp0, (p).y);                \
        ll[1] = __builtin_amdgcn_ds_bpermute(bp1, (p).y);                \
        ll[2] = __builtin_amdgcn_ds_bpermute(bp2, (p).y);                \
        ll[3] = __builtin_amdgcn_ds_bpermute(bp3, (p).y);                \
    } while (0)
#define GATHER(G, cc) do {                                               \
        _Pragma("unroll")                                                \
        for (int _u = 0; _u < 4; ++_u)                                   \
            G[_u] = *(const uint2*)(xs + ((((unsigned)cc[_u]) << 7) + vs8)); \
    } while (0)
#define CONSUME(G, ll) do {                                              \
        _Pragma("unroll")                                                \
        for (int _u = 0; _u < 4; ++_u) {                                 \
            float _l = __int_as_float(ll[_u]);                           \
            f32x2 _f0 = __builtin_amdgcn_cvt_pk_f32_fp8((int)G[_u].x, false); \
            f32x2 _f1 = __builtin_amdgcn_cvt_pk_f32_fp8((int)G[_u].x, true);  \
            f32x2 _f2 = __builtin_amdgcn_cvt_pk_f32_fp8((int)G[_u].y, false); \
            f32x2 _f3 = __builtin_amdgcn_cvt_pk_f32_fp8((int)G[_u].y, true);  \
            acc0 += _l * _f0.x; acc1 += _l * _f0.y;                      \
            acc2 += _l * _f1.x; acc3 += _l * _f1.y;                      \
            acc4 += _l * _f2.x; acc5 += _l * _f2.y;                      \
            acc6 += _l * _f3.x; acc7 += _l * _f3.y;                      \
        }                                                                \
    } while (0)

        int2 pA, pB;
        int cA[4], cB[4], lA[4], lB[4];
        uint2 GA[4], GB[4];

        LOADEP(pA, 0);
        BPERM(cA, lA, pA);
        GATHER(GA, cA);
        int it = 0;
        while (it + 2 <= niter) {
            LOADEP(pB, it + 1);
            BPERM(cB, lB, pB);
            GATHER(GB, cB);
            CONSUME(GA, lA);
            if (it + 2 < niter) {
                LOADEP(pA, it + 2);
                BPERM(cA, lA, pA);
                GATHER(GA, cA);
            }
            CONSUME(GB, lB);
            it += 2;
        }
        if (it < niter) CONSUME(GA, lA);   // odd leftover (in flight from prologue/loop)
#undef LOADEP
#undef BPERM
#undef GATHER
#undef CONSUME
    }
    // merge the 4 quadrants (channel c held by lanes s, s+16, s+32, s+48)
    acc0 += __shfl(acc0, lane ^ 16, 64); acc1 += __shfl(acc1, lane ^ 16, 64);
    acc2 += __shfl(acc2, lane ^ 16, 64); acc3 += __shfl(acc3, lane ^ 16, 64);
    acc4 += __shfl(acc4, lane ^ 16, 64); acc5 += __shfl(acc5, lane ^ 16, 64);
    acc6 += __shfl(acc6, lane ^ 16, 64); acc7 += __shfl(acc7, lane ^ 16, 64);
    acc0 += __shfl(acc0, lane ^ 32, 64); acc1 += __shfl(acc1, lane ^ 32, 64);
    acc2 += __shfl(acc2, lane ^ 32, 64); acc3 += __shfl(acc3, lane ^ 32, 64);
    acc4 += __shfl(acc4, lane ^ 32, 64); acc5 += __shfl(acc5, lane ^ 32, 64);
    acc6 += __shfl(acc6, lane ^ 32, 64); acc7 += __shfl(acc7, lane ^ 32, 64);
    if (q == 0) {
        float o0 = a * acc0, o1 = a * acc1, o2 = a * acc2, o3 = a * acc3;
        float o4 = a * acc4, o5 = a * acc5, o6 = a * acc6, o7 = a * acc7;
        if (zmode == 1) {
            uint4 zg = *((const uint4*)z + (size_t)r * 16 + s);
            o0 += b * bflo(zg.x); o1 += b * bfhi(zg.x);
            o2 += b * bflo(zg.y); o3 += b * bfhi(zg.y);
            o4 += b * bflo(zg.z); o5 += b * bfhi(zg.z);
            o6 += b * bflo(zg.w); o7 += b * bfhi(zg.w);
        } else if (zmode == 3) {
            const f32x4* zp = (const f32x4*)z + (size_t)r * 32 + s * 2;
            f32x4 z0 = zp[0], z1 = zp[1];
            o0 += b * z0.x; o1 += b * z0.y; o2 += b * z0.z; o3 += b * z0.w;
            o4 += b * z1.x; o5 += b * z1.y; o6 += b * z1.z; o7 += b * z1.w;
        }
        uint4 ob;
        ob.x = (unsigned)f2bf(o0) | ((unsigned)f2bf(o1) << 16);
        ob.y = (unsigned)f2bf(o2) | ((unsigned)f2bf(o3) << 16);
        ob.z = (unsigned)f2bf(o4) | ((unsigned)f2bf(o5) << 16);
        ob.w = (unsigned)f2bf(o6) | ((unsigned)f2bf(o7) << 16);
        *((uint4*)yb + (size_t)r * 16 + s) = ob;
        if (y8) {
            int pk0 = __builtin_amdgcn_cvt_pk_fp8_f32(o0, o1, 0, false);
            pk0 = __builtin_amdgcn_cvt_pk_fp8_f32(o2, o3, pk0, true);
            int pk1 = __builtin_amdgcn_cvt_pk_fp8_f32(o4, o5, 0, false);
            pk1 = __builtin_amdgcn_cvt_pk_fp8_f32(o6, o7, pk1, true);
            *((uint2*)y8 + (size_t)r * 16 + s) = make_uint2((unsigned)pk0, (unsigned)pk1);
        }
    }
}

// ---- fully-fused MFMA GEMM: out = x@W0 + t1@W1 + t2@W2 + t3@W3 + bias ----
// v3: weights staged in LDS. Diagnosis (r6): every wave re-read all 128 KB of
// wt through a 32 KB L1 -> ~800 MB of latency-chained L1-miss traffic at
// ~23 GB/s/CU = the entire 137 us. Now each BLOCK stages weights once
// (coalesced L2 stream, 200 MB total) and B-fragments come from LDS.
// Two phases of 64 KB (terms 0,1 then 2,3) keep LDS at 64 KB -> 2 blocks/CU.
// XOR chunk swizzle (chunk ^= row&15) on ds_write AND ds_read: linear layout
// would put all 16 m-lanes of a quad on one bank group (16-way conflict, G4).
// A-fragments for all 4 terms (64 VGPR) load up front: HBM latency hides under
// staging + phase-0 compute. LDS reused for transpose epilogue after a barrier.
__global__ void __launch_bounds__(256, 2) k_gemm4(
    const float* __restrict__ x,
    const unsigned short* __restrict__ t1,
    const unsigned short* __restrict__ t2,
    const unsigned short* __restrict__ t3,
    const unsigned short* __restrict__ wt,   // 4 x [128c][128k] bf16
    float* __restrict__ out, const float* __restrict__ bias)
{
    __shared__ uint4 ldsq[4096];             // 64 KiB: weight stage -> cbuf reuse
    char* lds = (char*)ldsq;
    int wv = threadIdx.x >> 6, lane = threadIdx.x & 63;
    int m = lane & 15, quad = lane >> 4;
    int r0 = blockIdx.x * 64 + wv * 16;
    int row = r0 + m;
    int rowc = (row >= N_NODES) ? (N_NODES - 1) : row;  // clamp fp32 x reads only

    // ---- A fragments for all 4 terms (issued first: HBM latency cover) ----
    bf16x8 a0[4], a1[4], a2[4], a3[4];
    {
        const float* p = x + (size_t)rowc * 128 + quad * 8;
#pragma unroll
        for (int kk = 0; kk < 4; ++kk) {
            f32x4 u = *(const f32x4*)(p + kk * 32);
            f32x4 v = *(const f32x4*)(p + kk * 32 + 4);
            bf16x8 fr;
            fr[0] = (short)f2bf(u.x); fr[1] = (short)f2bf(u.y);
            fr[2] = (short)f2bf(u.z); fr[3] = (short)f2bf(u.w);
            fr[4] = (short)f2bf(v.x); fr[5] = (short)f2bf(v.y);
            fr[6] = (short)f2bf(v.z); fr[7] = (short)f2bf(v.w);
            a0[kk] = fr;
        }
    }
    {
        const short* p = (const short*)t1 + (size_t)row * 128 + quad * 8;
#pragma unroll
        for (int kk = 0; kk < 4; ++kk) a1[kk] = *(const bf16x8*)(p + kk * 32);
    }
    {
        const short* p = (const short*)t2 + (size_t)row * 128 + quad * 8;
#pragma unroll
        for (int kk = 0; kk < 4; ++kk) a2[kk] = *(const bf16x8*)(p + kk * 32);
    }
    {
        const short* p = (const short*)t3 + (size_t)row * 128 + quad * 8;
#pragma unroll
        for (int kk = 0; kk < 4; ++kk) a3[kk] = *(const bf16x8*)(p + kk * 32);
    }

    f32x4 acc[8];
#pragma unroll
    for (int ct = 0; ct < 8; ++ct) acc[ct] = (f32x4){0.f, 0.f, 0.f, 0.f};

#pragma unroll
    for (int ph = 0; ph < 2; ++ph) {
        if (ph) __syncthreads();             // phase-0 ds_reads done before overwrite
        // stage 2 terms (64 KB = 4096 chunks of 16 B); chunk ^= row&15 swizzle
        const char* src = (const char*)wt + ph * 65536;
#pragma unroll
        for (int i = 0; i < 16; ++i) {
            int idx = i * 256 + (int)threadIdx.x;
            int g = idx >> 4, j = idx & 15;
            *(uint4*)(lds + g * 256 + ((unsigned)(j ^ (g & 15)) << 4)) =
                *(const uint4*)(src + idx * 16);
        }
        __syncthreads();
        // MFMA terms 2*ph and 2*ph+1, B from LDS (swizzled ds_read_b128)
#pragma unroll
        for (int tl = 0; tl < 2; ++tl) {
#pragma unroll
            for (int ct = 0; ct < 8; ++ct) {
#pragma unroll
                for (int kk = 0; kk < 4; ++kk) {
                    const bf16x8* B = (const bf16x8*)(lds + tl * 32768 + ct * 4096
                        + m * 256 + ((unsigned)(((quad + kk * 4) ^ m)) << 4));
                    bf16x8 av = (ph == 0) ? (tl == 0 ? a0[kk] : a1[kk])
                                          : (tl == 0 ? a2[kk] : a3[kk]);
                    acc[ct] = __builtin_amdgcn_mfma_f32_16x16x32_bf16(av, *B, acc[ct], 0, 0, 0);
                }
            }
        }
    }
    __syncthreads();                         // weights dead; reuse LDS as cbuf
    // stash C (C/D layout: col = ct*16+m, row = quad*4+i), then coalesced stores
    float* cw = (float*)lds + wv * (16 * 132);
#pragma unroll
    for (int ct = 0; ct < 8; ++ct)
#pragma unroll
        for (int i = 0; i < 4; ++i)
            cw[(quad * 4 + i) * 132 + ct * 16 + m] = acc[ct][i];
    int er = lane >> 2, ec = (lane & 3) * 32;
    int gr = r0 + er;
#pragma unroll
    for (int j = 0; j < 8; ++j) {
        f32x4 v = *(f32x4*)(cw + er * 132 + ec + j * 4);
        f32x4 bb = *(const f32x4*)(bias + ec + j * 4);
        v.x += bb.x; v.y += bb.y; v.z += bb.z; v.w += bb.w;
        if (gr < N_NODES)
            *(f32x4*)(out + (size_t)gr * 128 + ec + j * 4) = v;
    }
}

extern "C" void kernel_launch(void* const* d_in, const int* in_sizes, int n_in,
                              void* d_out, int out_size, void* d_ws, size_t ws_size,
                              hipStream_t stream) {
    const float* x    = (const float*)d_in[0];
    const float* lap  = (const float*)d_in[1];
    const float* w    = (const float*)d_in[2];
    const float* bias = (const float*)d_in[3];
    const int*   ei   = (const int*)d_in[4];
    float* out = (float*)d_out;

    char* ws = (char*)d_ws;
    const size_t SZ_BF = (size_t)ROWS_PAD * 128 * 2;   // 25,608,192 B
    const size_t SZ_F8 = (size_t)ROWS_PAD * 128;       // 12,804,096 B
    const size_t SZ_EP = SZ_BF + 1024;                 // ep + 64 zero pad slots (+ slack)
    // layout (lifetimes annotated):
    int2* ep            = (int2*)(ws);                              // dead after spmm3
    unsigned char* xf8  = (unsigned char*)(ws + SZ_EP);             // dead after SpMM1
    unsigned char* t1_8 = (unsigned char*)(ws + SZ_EP + SZ_F8);     // dead after SpMM2
    unsigned char* t3_b = (unsigned char*)(ws + SZ_EP);             // reuses xf8+t1_8 region (bf16)
    unsigned char* t1_b = (unsigned char*)(ws + SZ_EP + SZ_BF);
    unsigned char* t2_8 = (unsigned char*)(ws + SZ_EP + 2 * SZ_BF);
    unsigned char* t2_b = (unsigned char*)(ws + SZ_EP + 2 * SZ_BF + SZ_F8);
    uint2* ep_tmp       = (uint2*)(ws + SZ_EP + 2 * SZ_BF);         // aliases t2_8 + t2_b head; dead after rsort
    char* p = ws + SZ_EP + 3 * SZ_BF + SZ_F8;
    int* rowstart = (int*)p; p += 400128;
    int* bcnt     = (int*)p; p += 3200;
    int* bbase    = (int*)p; p += 3200;
    int* bcursor  = (int*)p; p += 3200;
    unsigned short* wt = (unsigned short*)p;           // 4*128*128 bf16

    hipMemsetAsync(bcnt, 0, N_BUCKETS * sizeof(int), stream);
    k_convert_x<<<1024, 256, 0, stream>>>(x, (unsigned*)xf8);
    k_convert_w<<<256, 256, 0, stream>>>(w, wt);
    k_bhist<<<(N_EDGES + 8191) / 8192, 256, 0, stream>>>(ei, bcnt);
    k_bscan<<<1, 1024, 0, stream>>>(bcnt, bbase, bcursor, rowstart, ep);
    k_bin<<<(N_EDGES + 16383) / 16384, 1024, 0, stream>>>(ei, lap, bcursor, ep_tmp);
    k_rsort<<<N_BUCKETS, 256, 0, stream>>>(ep_tmp, bbase, rowstart, ep);

    // Tx1 = L x            (gather fp8 x; write bf16 + fp8)
    k_spmm8<<<ROWS_PAD / 4, 256, 0, stream>>>(xf8, nullptr, 0,
        (unsigned*)t1_8, (uint2*)t1_b, rowstart, ep, 1.f, 0.f);
    // Tx2 = 2 L Tx1 - x    (gather fp8 Tx1; z fp32 x; write bf16 + fp8)
    k_spmm8<<<ROWS_PAD / 4, 256, 0, stream>>>(t1_8, x, 3,
        (unsigned*)t2_8, (uint2*)t2_b, rowstart, ep, 2.f, -1.f);
    // Tx3 = 2 L Tx2 - Tx1  (gather fp8 Tx2; z bf16 Tx1; write bf16 only, into dead xf8/t1_8 region)
    k_spmm8<<<ROWS_PAD / 4, 256, 0, stream>>>(t2_8, t1_b, 1,
        nullptr, (uint2*)t3_b, rowstart, ep, 2.f, -1.f);
    // out = x@W0 + Tx1@W1 + Tx2@W2 + Tx3@W3 + bias   (single fused GEMM, LDS-staged W)
    k_gemm4<<<ROWS_PAD / 64, 256, 0, stream>>>(x, (const unsigned short*)t1_b,
        (const unsigned short*)t2_b, (const unsigned short*)t3_b, wt, out, bias);
}